// Round 8
// baseline (36.796 us; speedup 1.0000x reference)
//
#include <hip/hip_runtime.h>

// Problem constants
#define NB 8
#define CH 64
#define KP 8            // K = C/8
#define HWP 4096        // H*W
#define QSPLIT 8        // q-split factor
#define QCHUNK (HWP / QSPLIT)   // 512 q per chunk
#define NHW (NB * HWP)  // 32768

typedef float f32x16 __attribute__((ext_vector_type(16)));
typedef __bf16 bf16x8 __attribute__((ext_vector_type(8)));
typedef short short8v __attribute__((ext_vector_type(8)));

// Workspace layout (float offsets)
#define WS_FB  0                        // f bf16 [NB][HWP][8], pre-scaled by log2(e)
#define WS_GB  (WS_FB + NHW * 4)        // g bf16 [NB][HWP][8]
#define WS_SB  (WS_GB + NHW * 4)        // s bf16 [NB][HWP], PRE-SHUFFLED per 16
#define WS_PL  (WS_SB + NHW / 2)        // partial l   [QSPLIT][NHW]
#define WS_PA  (WS_PL + QSPLIT * NHW)   // partial acc [QSPLIT][NHW]

// s shuffle: within each 16-block, position j holds s[porder[j]],
// porder = {0,1,2,3, 8,9,10,11, 4,5,6,7, 12,13,14,15} (an involution).
// Makes PV MFMA A-frag k-order match the e-tile C-reg q-order (verified R6).
__device__ __forceinline__ int s_shuf_idx(int i) {
    return i ^ (((((i >> 2) ^ (i >> 3)) & 1) != 0) ? 12 : 0);
}

// ---------------------------------------------------------------------------
// Kernel 1: 1x1-conv projections (unchanged — ~2-3 us, not the bottleneck).
// ---------------------------------------------------------------------------
__global__ __launch_bounds__(128) void proj_kernel(
    const float* __restrict__ x,
    const float* __restrict__ Wf, const float* __restrict__ bf,
    const float* __restrict__ Wg, const float* __restrict__ bg,
    const float* __restrict__ Ws, const float* __restrict__ bs,
    float* __restrict__ ws)
{
    int blk = blockIdx.x;                 // 256 blocks: 32 per batch
    int n = blk >> 5;
    int p = ((blk & 31) << 7) + threadIdx.x;
    const float* xp = x + (size_t)n * CH * HWP + p;

    float accf[KP], accg[KP], accs;
#pragma unroll
    for (int k = 0; k < KP; ++k) { accf[k] = bf[k]; accg[k] = bg[k]; }
    accs = bs[0];

#pragma unroll 16
    for (int c = 0; c < CH; ++c) {
        float xv = xp[(size_t)c * HWP];
#pragma unroll
        for (int k = 0; k < KP; ++k) {
            accf[k] = fmaf(Wf[k * CH + c], xv, accf[k]);
            accg[k] = fmaf(Wg[k * CH + c], xv, accg[k]);
        }
        accs = fmaf(Ws[c], xv, accs);
    }

    const float L2E = 1.4426950408889634f;
    bf16x8 fv, gv;
#pragma unroll
    for (int k = 0; k < KP; ++k) {
        fv[k] = (__bf16)(accf[k] * L2E);
        gv[k] = (__bf16)accg[k];
    }

    ushort* fb = (ushort*)(ws + WS_FB) + (size_t)(n * HWP + p) * 8;
    ushort* gb = (ushort*)(ws + WS_GB) + (size_t)(n * HWP + p) * 8;
    *(short8v*)fb = __builtin_bit_cast(short8v, fv);
    *(short8v*)gb = __builtin_bit_cast(short8v, gv);

    __bf16 sb16 = (__bf16)accs;
    ushort* sb = (ushort*)(ws + WS_SB);
    sb[(size_t)n * HWP + (p & ~15) + s_shuf_idx(p & 15)] =
        __builtin_bit_cast(ushort, sb16);
}

// ---------------------------------------------------------------------------
// Kernel 2: MFMA flash-attention partials (no-max, log2-domain, PV on MFMA).
// R8: 2-stage LDS prefetch (next iter's afrag/a1/a2 issued before the
// exp/cvt block, hiding ~120cy LDS latency) + dual independent PV
// accumulators (no intra-iter MFMA chaining). 15 pipelined iters + epilogue.
// ---------------------------------------------------------------------------
__global__ __launch_bounds__(256, 4) void attn_mfma_kernel(float* __restrict__ ws)
{
    __shared__ alignas(16) ushort g_lds[(QCHUNK + 1) * 8];  // 8.2 KiB (+ zero row)
    __shared__ alignas(16) ushort s_lds[QCHUNK];            // 1 KiB (shuffled bf16)
    __shared__ alignas(16) ushort ones_lds[32];             // 64 B of bf16 1.0

    const int b     = blockIdx.x;          // 2048 = n(8) * pblk(32) * chunk(8)
    const int chunk = b & (QSPLIT - 1);
    const int pblk  = (b >> 3) & 31;
    const int n     = b >> 8;
    const int tid   = threadIdx.x;
    const int lane  = tid & 63;
    const int wv    = tid >> 6;
    const int l31   = lane & 31;
    const int hi    = lane >> 5;
    const int q0    = chunk * QCHUNK;

    // ---- stage g chunk + zero row + shuffled-s chunk + ones ----
    {
        const float4* gsrc = (const float4*)(ws + WS_GB) + ((size_t)n * HWP + q0);
        float4* gdst = (float4*)g_lds;
        gdst[tid]       = gsrc[tid];
        gdst[tid + 256] = gsrc[tid + 256];
        if (tid == 0) gdst[QCHUNK] = make_float4(0.f, 0.f, 0.f, 0.f);
        if (tid < QCHUNK / 8)
            ((float4*)s_lds)[tid] =
                ((const float4*)((const ushort*)(ws + WS_SB) + (size_t)n * HWP + q0))[tid];
        if (tid < 16) ((uint*)ones_lds)[tid] = 0x3F803F80u;
    }

    // ---- B-fragment (score): f rows for this wave's 32 p (lanes 0-31 real) ----
    const int p0 = (pblk << 7) + (wv << 5);
    const ushort* fbase = (const ushort*)(ws + WS_FB) + (size_t)n * HWP * 8;
    short8v z8 = {0, 0, 0, 0, 0, 0, 0, 0};
    bf16x8 bfrag = __builtin_bit_cast(bf16x8,
        hi ? z8 : *(const short8v*)(fbase + (size_t)(p0 + l31) * 8));

    // per-lane walking pointers:
    // g row: hi lanes pinned to the zero row (stride 0); lo lanes walk 32 rows.
    const ushort* gptr = g_lds + (size_t)(hi ? QCHUNK : l31) * 8;
    const int gstride = hi ? 0 : 32 * 8;           // ushorts per iteration
    // A_s: row-1 lanes pinned to ones (stride 0); others walk shuffled s.
    const ushort* aptr = (l31 == 1) ? ones_lds : (s_lds + (hi << 3));
    const int astride = (l31 == 1) ? 0 : 32;       // ushorts per iteration

    __syncthreads();

    const f32x16 czero = {0.f};
    f32x16 c_pv0 = {0.f};
    f32x16 c_pv1 = {0.f};

    // pipeline preload (iteration 0's operands)
    bf16x8 afragN = __builtin_bit_cast(bf16x8, *(const short8v*)gptr);
    short8v a1N = *(const short8v*)aptr;
    short8v a2N = *(const short8v*)(aptr + 16);
    gptr += gstride;
    aptr += astride;

#pragma unroll 1
    for (int qt = 0; qt < QCHUNK / 32 - 1; ++qt) {   // 15 pipelined iterations
        bf16x8 afrag = afragN;
        bf16x8 a1 = __builtin_bit_cast(bf16x8, a1N);
        bf16x8 a2 = __builtin_bit_cast(bf16x8, a2N);

        // issue next iteration's LDS loads (latency hides under exp/cvt)
        afragN = __builtin_bit_cast(bf16x8, *(const short8v*)gptr);
        a1N = *(const short8v*)aptr;
        a2N = *(const short8v*)(aptr + 16);
        gptr += gstride;
        aptr += astride;

        f32x16 c = __builtin_amdgcn_mfma_f32_32x32x16_bf16(afrag, bfrag, czero, 0, 0, 0);
#pragma unroll
        for (int r = 0; r < 16; ++r) c[r] = __builtin_amdgcn_exp2f(c[r]);

        bf16x8 elo, ehi;
#pragma unroll
        for (int r = 0; r < 8; ++r) { elo[r] = (__bf16)c[r]; ehi[r] = (__bf16)c[r + 8]; }

        c_pv0 = __builtin_amdgcn_mfma_f32_32x32x16_bf16(a1, elo, c_pv0, 0, 0, 0);
        c_pv1 = __builtin_amdgcn_mfma_f32_32x32x16_bf16(a2, ehi, c_pv1, 0, 0, 0);
    }

    // epilogue iteration (no prefetch)
    {
        f32x16 c = __builtin_amdgcn_mfma_f32_32x32x16_bf16(afragN, bfrag, czero, 0, 0, 0);
#pragma unroll
        for (int r = 0; r < 16; ++r) c[r] = __builtin_amdgcn_exp2f(c[r]);

        bf16x8 elo, ehi;
#pragma unroll
        for (int r = 0; r < 8; ++r) { elo[r] = (__bf16)c[r]; ehi[r] = (__bf16)c[r + 8]; }

        c_pv0 = __builtin_amdgcn_mfma_f32_32x32x16_bf16(
            __builtin_bit_cast(bf16x8, a1N), elo, c_pv0, 0, 0, 0);
        c_pv1 = __builtin_amdgcn_mfma_f32_32x32x16_bf16(
            __builtin_bit_cast(bf16x8, a2N), ehi, c_pv1, 0, 0, 0);
    }

    // D rows: 0 = sum e*s, 1 = sum e; cols = p (regs 0,1 of hi=0 lanes).
    if (!hi) {
        size_t base = (size_t)chunk * NHW + (size_t)n * HWP + p0;
        ws[WS_PA + base + l31] = c_pv0[0] + c_pv1[0];
        ws[WS_PL + base + l31] = c_pv0[1] + c_pv1[1];
    }
}

// ---------------------------------------------------------------------------
// Kernel 3 (fused merge + epilogue): per block = (n, 64-p tile), 512 blocks:
// reduce QSPLIT partials -> att (write att_map), then out = att*gamma + x.
// ---------------------------------------------------------------------------
__global__ __launch_bounds__(256) void finish_kernel(
    const float* __restrict__ x, const float* __restrict__ ws,
    const float* __restrict__ gamma, float* __restrict__ out)
{
    __shared__ float att_lds[64];
    const int blk = blockIdx.x;        // 512 = n(8) * pt(64)
    const int n   = blk >> 6;
    const int p0  = (blk & 63) << 6;
    const int tid = threadIdx.x;

    if (tid < 64) {
        size_t row = (size_t)n * HWP + p0 + tid;
        float l = 0.f, a = 0.f;
#pragma unroll
        for (int c = 0; c < QSPLIT; ++c) {
            l += ws[WS_PL + (size_t)c * NHW + row];
            a += ws[WS_PA + (size_t)c * NHW + row];
        }
        float att = a / l;
        att_lds[tid] = att;
        out[row] = att;                // att_map output
    }
    __syncthreads();

    const float gm = gamma[0];
    float* outp = out + NHW;
#pragma unroll
    for (int it = 0; it < 4; ++it) {
        int idx = it * 256 + tid;      // 0..1023 over (c, p/4)
        int c   = idx >> 4;
        int p4  = (idx & 15) << 2;
        size_t off = (size_t)n * CH * HWP + (size_t)c * HWP + p0 + p4;
        float4 xv = *(const float4*)(x + off);
        float4 av = *(const float4*)(att_lds + p4);
        float4 o;
        o.x = fmaf(av.x, gm, xv.x);
        o.y = fmaf(av.y, gm, xv.y);
        o.z = fmaf(av.z, gm, xv.z);
        o.w = fmaf(av.w, gm, xv.w);
        *(float4*)(outp + off) = o;
    }
}

extern "C" void kernel_launch(void* const* d_in, const int* in_sizes, int n_in,
                              void* d_out, int out_size, void* d_ws, size_t ws_size,
                              hipStream_t stream) {
    const float* x     = (const float*)d_in[0];
    const float* Wf    = (const float*)d_in[1];
    const float* bf    = (const float*)d_in[2];
    const float* Wg    = (const float*)d_in[3];
    const float* bg    = (const float*)d_in[4];
    const float* Ws    = (const float*)d_in[5];
    const float* bs    = (const float*)d_in[6];
    const float* gamma = (const float*)d_in[7];
    float* out = (float*)d_out;
    float* ws  = (float*)d_ws;

    // d_out layout: att_map [NB*HWP] then output [NB*CH*HWP]
    proj_kernel<<<NB * (HWP / 128), 128, 0, stream>>>(x, Wf, bf, Wg, bg, Ws, bs, ws);
    attn_mfma_kernel<<<NB * 32 * QSPLIT, 256, 0, stream>>>(ws);
    finish_kernel<<<NB * 64, 256, 0, stream>>>(x, ws, gamma, out);
}

// Round 10
// 36.385 us; speedup vs baseline: 1.0113x; 1.0113x over previous
//
#include <hip/hip_runtime.h>

// Problem constants
#define NB 8
#define CH 64
#define KP 8            // K = C/8
#define HWP 4096        // H*W
#define NHW (NB * HWP)  // 32768
#define PTILE 64        // p-rows per attn block
#define QC 512          // q staging chunk
#define NCHUNK (HWP / QC)   // 8

typedef float f32x16 __attribute__((ext_vector_type(16)));
typedef __bf16 bf16x8 __attribute__((ext_vector_type(8)));
typedef short short8v __attribute__((ext_vector_type(8)));

// Workspace layout (float offsets)
#define WS_FB  0                 // f bf16 [NB][HWP][8], pre-scaled by log2(e)
#define WS_GB  (NHW * 4)         // g bf16 [NB][HWP][8]
#define WS_SB  (NHW * 8)         // s bf16 [NB][HWP], pre-shuffled per 16

// s shuffle: within each 16-block, position j holds s[porder[j]],
// porder = {0,1,2,3, 8,9,10,11, 4,5,6,7, 12,13,14,15} (involution).
// Makes PV MFMA A-frag k-order match the e-tile C-reg q-order (verified R6-R8).
__device__ __forceinline__ int s_shuf_idx(int i) {
    return i ^ (((((i >> 2) ^ (i >> 3)) & 1) != 0) ? 12 : 0);
}

// ---------------------------------------------------------------------------
// Kernel 1: 1x1-conv projections (R8-verified). f pre-scaled by log2(e);
// f,g bf16 rows of 8; s bf16 pre-shuffled.
// ---------------------------------------------------------------------------
__global__ __launch_bounds__(128) void proj_kernel(
    const float* __restrict__ x,
    const float* __restrict__ Wf, const float* __restrict__ bf,
    const float* __restrict__ Wg, const float* __restrict__ bg,
    const float* __restrict__ Ws, const float* __restrict__ bs,
    float* __restrict__ ws)
{
    int blk = blockIdx.x;                 // 256 blocks: 32 per batch
    int n = blk >> 5;
    int p = ((blk & 31) << 7) + threadIdx.x;
    const float* xp = x + (size_t)n * CH * HWP + p;

    float accf[KP], accg[KP], accs;
#pragma unroll
    for (int k = 0; k < KP; ++k) { accf[k] = bf[k]; accg[k] = bg[k]; }
    accs = bs[0];

#pragma unroll 16
    for (int c = 0; c < CH; ++c) {
        float xv = xp[(size_t)c * HWP];
#pragma unroll
        for (int k = 0; k < KP; ++k) {
            accf[k] = fmaf(Wf[k * CH + c], xv, accf[k]);
            accg[k] = fmaf(Wg[k * CH + c], xv, accg[k]);
        }
        accs = fmaf(Ws[c], xv, accs);
    }

    const float L2E = 1.4426950408889634f;
    bf16x8 fv, gv;
#pragma unroll
    for (int k = 0; k < KP; ++k) {
        fv[k] = (__bf16)(accf[k] * L2E);
        gv[k] = (__bf16)accg[k];
    }

    ushort* fb = (ushort*)(ws + WS_FB) + (size_t)(n * HWP + p) * 8;
    ushort* gb = (ushort*)(ws + WS_GB) + (size_t)(n * HWP + p) * 8;
    *(short8v*)fb = __builtin_bit_cast(short8v, fv);
    *(short8v*)gb = __builtin_bit_cast(short8v, gv);

    __bf16 sb16 = (__bf16)accs;
    ushort* sb = (ushort*)(ws + WS_SB);
    sb[(size_t)n * HWP + (p & ~15) + s_shuf_idx(p & 15)] =
        __builtin_bit_cast(ushort, sb16);
}

// ---------------------------------------------------------------------------
// Kernel 2 (fused attn + merge + epilogue). Block = (n, 64 p-rows), 512 thr
// = 8 waves: pg = w&1 (32-p group), qs = w>>2..  (4 q-splits of 128 q/chunk).
// Sweeps all 4096 q in 8 double-buffered 512-q LDS chunks. Inner 32qx32p
// tile math identical to R6-R8 (score MFMA -> 16 exp2 -> 2 PV MFMAs).
// Then LDS-reduce the 4 q-split partials -> att; write att_map and
// out = att*gamma + x directly. No partial HBM round-trip, no 3rd dispatch.
// ---------------------------------------------------------------------------
__global__ __launch_bounds__(512, 4) void attn_finish_kernel(
    const float* __restrict__ x, const float* __restrict__ gamma,
    float* __restrict__ ws, float* __restrict__ out)
{
    __shared__ alignas(16) ushort g_lds[2][(QC + 1) * KP];  // 16.4 KB (+zero rows)
    __shared__ alignas(16) ushort s_lds[2][QC];             // 2 KB
    __shared__ ushort ones_lds[32];                         // 64 B
    __shared__ float  part_l[4][PTILE];                     // 1 KB
    __shared__ float  part_a[4][PTILE];                     // 1 KB
    __shared__ float  att_lds[PTILE];                       // 256 B

    const int blk  = blockIdx.x;       // 512 = n(8) * ptile(64)
    const int n    = blk >> 6;
    const int p0   = (blk & 63) << 6;
    const int tid  = threadIdx.x;
    const int lane = tid & 63;
    const int w    = tid >> 6;         // 0..7
    const int pg   = w & 1;            // p-group (32 rows)
    const int qs   = w >> 1;           // q-split 0..3
    const int l31  = lane & 31;
    const int hi   = lane >> 5;

    if (tid < 16) ((uint*)ones_lds)[tid] = 0x3F803F80u;     // bf16 1.0 pairs
    if (tid < 8) { g_lds[0][QC * KP + tid] = 0; g_lds[1][QC * KP + tid] = 0; }

    // B-fragment: f rows for this wave's 32 p (lanes 0-31 real)
    const ushort* fbase = (const ushort*)(ws + WS_FB) + (size_t)n * HWP * KP;
    short8v z8 = {0, 0, 0, 0, 0, 0, 0, 0};
    bf16x8 bfrag = __builtin_bit_cast(bf16x8,
        hi ? z8 : *(const short8v*)(fbase + (size_t)(p0 + pg * 32 + l31) * KP));

    const float4* gsrc = (const float4*)((const ushort*)(ws + WS_GB) +
                                         (size_t)n * HWP * KP);
    const float4* ssrc = (const float4*)((const ushort*)(ws + WS_SB) +
                                         (size_t)n * HWP);

    const f32x16 czero = {0.f};
    f32x16 c_pv0 = {0.f};
    f32x16 c_pv1 = {0.f};

    // stage chunk 0
    ((float4*)g_lds[0])[tid] = gsrc[tid];
    if (tid < QC / 8) ((float4*)s_lds[0])[tid] = ssrc[tid];
    __syncthreads();

#pragma unroll 1
    for (int j = 0; j < NCHUNK; ++j) {
        const int buf = j & 1;
        if (j + 1 < NCHUNK) {          // prefetch next chunk into other buffer
            ((float4*)g_lds[buf ^ 1])[tid] = gsrc[(j + 1) * QC + tid];
            if (tid < QC / 8)
                ((float4*)s_lds[buf ^ 1])[tid] = ssrc[(j + 1) * (QC / 8) + tid];
        }
        const ushort* gb = g_lds[buf];
        const ushort* sb = s_lds[buf];

#pragma unroll 1
        for (int t = 0; t < 4; ++t) {
            const int ql = qs * 128 + t * 32;    // q offset within chunk
            int arow = hi ? QC : (ql + l31);
            bf16x8 afrag = __builtin_bit_cast(bf16x8,
                *(const short8v*)(gb + (size_t)arow * KP));

            f32x16 c = __builtin_amdgcn_mfma_f32_32x32x16_bf16(
                afrag, bfrag, czero, 0, 0, 0);
#pragma unroll
            for (int r = 0; r < 16; ++r) c[r] = __builtin_amdgcn_exp2f(c[r]);

            bf16x8 elo, ehi;
#pragma unroll
            for (int r = 0; r < 8; ++r) { elo[r] = (__bf16)c[r]; ehi[r] = (__bf16)c[r + 8]; }

            const ushort* ap = (l31 == 1) ? ones_lds : (sb + ql + (hi << 3));
            bf16x8 a1 = __builtin_bit_cast(bf16x8, *(const short8v*)ap);
            bf16x8 a2 = __builtin_bit_cast(bf16x8, *(const short8v*)(ap + 16));

            c_pv0 = __builtin_amdgcn_mfma_f32_32x32x16_bf16(a1, elo, c_pv0, 0, 0, 0);
            c_pv1 = __builtin_amdgcn_mfma_f32_32x32x16_bf16(a2, ehi, c_pv1, 0, 0, 0);
        }
        __syncthreads();   // buf consumed by all; buf^1 staged for next iter
    }

    // partials: D rows 0 = sum e*s, 1 = sum e (regs 0,1 of hi=0 lanes)
    if (!hi) {
        part_a[qs][pg * 32 + l31] = c_pv0[0] + c_pv1[0];
        part_l[qs][pg * 32 + l31] = c_pv0[1] + c_pv1[1];
    }
    __syncthreads();

    // merge + att_map output
    if (tid < PTILE) {
        float l = (part_l[0][tid] + part_l[1][tid]) + (part_l[2][tid] + part_l[3][tid]);
        float a = (part_a[0][tid] + part_a[1][tid]) + (part_a[2][tid] + part_a[3][tid]);
        float att = a / l;
        att_lds[tid] = att;
        out[(size_t)n * HWP + p0 + tid] = att;
    }
    __syncthreads();

    // epilogue: out = att*gamma + x for this (n, 64-p) tile, all 64 channels
    const float gm = gamma[0];
    const float* xn = x + (size_t)n * CH * HWP + p0;
    float* outp = out + NHW + (size_t)n * CH * HWP + p0;
#pragma unroll
    for (int it = 0; it < 2; ++it) {
        int idx = it * 512 + tid;      // 1024 float4s over (c, p/4)
        int c   = idx >> 4;
        int p4  = (idx & 15) << 2;
        float4 xv = *(const float4*)(xn + (size_t)c * HWP + p4);
        float4 av = *(const float4*)(att_lds + p4);
        float4 o;
        o.x = fmaf(av.x, gm, xv.x);
        o.y = fmaf(av.y, gm, xv.y);
        o.z = fmaf(av.z, gm, xv.z);
        o.w = fmaf(av.w, gm, xv.w);
        *(float4*)(outp + (size_t)c * HWP + p4) = o;
    }
}

extern "C" void kernel_launch(void* const* d_in, const int* in_sizes, int n_in,
                              void* d_out, int out_size, void* d_ws, size_t ws_size,
                              hipStream_t stream) {
    const float* x     = (const float*)d_in[0];
    const float* Wf    = (const float*)d_in[1];
    const float* bf    = (const float*)d_in[2];
    const float* Wg    = (const float*)d_in[3];
    const float* bg    = (const float*)d_in[4];
    const float* Ws    = (const float*)d_in[5];
    const float* bs    = (const float*)d_in[6];
    const float* gamma = (const float*)d_in[7];
    float* out = (float*)d_out;
    float* ws  = (float*)d_ws;

    // d_out layout: att_map [NB*HWP] then output [NB*CH*HWP]
    proj_kernel<<<NB * (HWP / 128), 128, 0, stream>>>(x, Wf, bf, Wg, bg, Ws, bs, ws);
    attn_finish_kernel<<<NB * (HWP / PTILE), 512, 0, stream>>>(x, gamma, ws, out);
}

// Round 11
// 36.324 us; speedup vs baseline: 1.0130x; 1.0017x over previous
//
#include <hip/hip_runtime.h>

// Problem constants
#define NB 8
#define CH 64
#define KP 8            // K = C/8
#define HWP 4096        // H*W
#define NHW (NB * HWP)  // 32768
#define PTILE 64        // p-rows per attn block
#define QC 512          // q staging chunk
#define NCHUNK (HWP / QC)   // 8

typedef float f32x16 __attribute__((ext_vector_type(16)));
typedef __bf16 bf16x8 __attribute__((ext_vector_type(8)));
typedef short short8v __attribute__((ext_vector_type(8)));

// Workspace layout (float offsets)
#define WS_FB  0                 // f bf16 [NB][HWP][8], pre-scaled by log2(e)
#define WS_GB  (NHW * 4)         // g bf16 [NB][HWP][8]
#define WS_SB  (NHW * 8)         // s bf16 [NB][HWP], pre-shuffled per 16

// s shuffle: within each 16-block, position j holds s[porder[j]],
// porder = {0,1,2,3, 8,9,10,11, 4,5,6,7, 12,13,14,15} (involution).
// Makes PV MFMA A-frag k-order match the e-tile C-reg q-order (verified R6-R10).
__device__ __forceinline__ int s_shuf_idx(int i) {
    return i ^ (((((i >> 2) ^ (i >> 3)) & 1) != 0) ? 12 : 0);
}

// ---------------------------------------------------------------------------
// Kernel 1: 1x1-conv projections (R8-verified, unchanged).
// ---------------------------------------------------------------------------
__global__ __launch_bounds__(128) void proj_kernel(
    const float* __restrict__ x,
    const float* __restrict__ Wf, const float* __restrict__ bf,
    const float* __restrict__ Wg, const float* __restrict__ bg,
    const float* __restrict__ Ws, const float* __restrict__ bs,
    float* __restrict__ ws)
{
    int blk = blockIdx.x;                 // 256 blocks: 32 per batch
    int n = blk >> 5;
    int p = ((blk & 31) << 7) + threadIdx.x;
    const float* xp = x + (size_t)n * CH * HWP + p;

    float accf[KP], accg[KP], accs;
#pragma unroll
    for (int k = 0; k < KP; ++k) { accf[k] = bf[k]; accg[k] = bg[k]; }
    accs = bs[0];

#pragma unroll 16
    for (int c = 0; c < CH; ++c) {
        float xv = xp[(size_t)c * HWP];
#pragma unroll
        for (int k = 0; k < KP; ++k) {
            accf[k] = fmaf(Wf[k * CH + c], xv, accf[k]);
            accg[k] = fmaf(Wg[k * CH + c], xv, accg[k]);
        }
        accs = fmaf(Ws[c], xv, accs);
    }

    const float L2E = 1.4426950408889634f;
    bf16x8 fv, gv;
#pragma unroll
    for (int k = 0; k < KP; ++k) {
        fv[k] = (__bf16)(accf[k] * L2E);
        gv[k] = (__bf16)accg[k];
    }

    ushort* fb = (ushort*)(ws + WS_FB) + (size_t)(n * HWP + p) * 8;
    ushort* gb = (ushort*)(ws + WS_GB) + (size_t)(n * HWP + p) * 8;
    *(short8v*)fb = __builtin_bit_cast(short8v, fv);
    *(short8v*)gb = __builtin_bit_cast(short8v, gv);

    __bf16 sb16 = (__bf16)accs;
    ushort* sb = (ushort*)(ws + WS_SB);
    sb[(size_t)n * HWP + (p & ~15) + s_shuf_idx(p & 15)] =
        __builtin_bit_cast(ushort, sb16);
}

// ---------------------------------------------------------------------------
// Kernel 2 (fused attn + merge + epilogue). Block = (n, 64 p-rows), 512 thr
// = 8 waves: pg = w&1 (32-p group), qs = w>>1 (4 q-splits of 128 q/chunk).
// Sweeps all 4096 q in 8 double-buffered 512-q LDS chunks (R10-verified).
// R11: the block's 16 KB x tile is ALSO staged into LDS, one 2 KB slice per
// chunk, riding the same async-stage window as g/s — hides the 33.5 MB x
// re-read under the sweep. Epilogue reads x from LDS (write-only tail).
// ---------------------------------------------------------------------------
__global__ __launch_bounds__(512, 4) void attn_finish_kernel(
    const float* __restrict__ x, const float* __restrict__ gamma,
    float* __restrict__ ws, float* __restrict__ out)
{
    __shared__ alignas(16) ushort g_lds[2][(QC + 1) * KP];  // 16.4 KB (+zero rows)
    __shared__ alignas(16) ushort s_lds[2][QC];             // 2 KB
    __shared__ alignas(16) float  x_tile[CH * PTILE];       // 16 KB, f4 idx: c=f>>4 p4=(f&15)*4
    __shared__ ushort ones_lds[32];                         // 64 B
    __shared__ float  part_l[4][PTILE];                     // 1 KB
    __shared__ float  part_a[4][PTILE];                     // 1 KB
    __shared__ float  att_lds[PTILE];                       // 256 B

    const int blk  = blockIdx.x;       // 512 = n(8) * ptile(64)
    const int n    = blk >> 6;
    const int p0   = (blk & 63) << 6;
    const int tid  = threadIdx.x;
    const int lane = tid & 63;
    const int w    = tid >> 6;         // 0..7
    const int pg   = w & 1;            // p-group (32 rows)
    const int qs   = w >> 1;           // q-split 0..3
    const int l31  = lane & 31;
    const int hi   = lane >> 5;

    if (tid < 16) ((uint*)ones_lds)[tid] = 0x3F803F80u;     // bf16 1.0 pairs
    if (tid < 8) { g_lds[0][QC * KP + tid] = 0; g_lds[1][QC * KP + tid] = 0; }

    // B-fragment: f rows for this wave's 32 p (lanes 0-31 real)
    const ushort* fbase = (const ushort*)(ws + WS_FB) + (size_t)n * HWP * KP;
    short8v z8 = {0, 0, 0, 0, 0, 0, 0, 0};
    bf16x8 bfrag = __builtin_bit_cast(bf16x8,
        hi ? z8 : *(const short8v*)(fbase + (size_t)(p0 + pg * 32 + l31) * KP));

    const float4* gsrc = (const float4*)((const ushort*)(ws + WS_GB) +
                                         (size_t)n * HWP * KP);
    const float4* ssrc = (const float4*)((const ushort*)(ws + WS_SB) +
                                         (size_t)n * HWP);
    const float* xn = x + (size_t)n * CH * HWP + p0;

    const f32x16 czero = {0.f};
    f32x16 c_pv0 = {0.f};
    f32x16 c_pv1 = {0.f};

    // stage chunk 0
    ((float4*)g_lds[0])[tid] = gsrc[tid];
    if (tid < QC / 8) ((float4*)s_lds[0])[tid] = ssrc[tid];
    __syncthreads();

#pragma unroll 1
    for (int j = 0; j < NCHUNK; ++j) {
        const int buf = j & 1;
        if (j + 1 < NCHUNK) {          // prefetch next g/s chunk into other buffer
            ((float4*)g_lds[buf ^ 1])[tid] = gsrc[(j + 1) * QC + tid];
            if (tid < QC / 8)
                ((float4*)s_lds[buf ^ 1])[tid] = ssrc[(j + 1) * (QC / 8) + tid];
        }
        // x-tile slice j (2 KB): load rides the same async window; the
        // compiler sinks vmcnt+ds_write below the MFMA/exp2 block (T14).
        if (tid < 128) {
            int f = (j << 7) + tid;
            ((float4*)x_tile)[f] =
                *(const float4*)(xn + (size_t)(f >> 4) * HWP + ((f & 15) << 2));
        }
        const ushort* gb = g_lds[buf];
        const ushort* sb = s_lds[buf];

#pragma unroll 1
        for (int t = 0; t < 4; ++t) {
            const int ql = qs * 128 + t * 32;    // q offset within chunk
            int arow = hi ? QC : (ql + l31);
            bf16x8 afrag = __builtin_bit_cast(bf16x8,
                *(const short8v*)(gb + (size_t)arow * KP));

            f32x16 c = __builtin_amdgcn_mfma_f32_32x32x16_bf16(
                afrag, bfrag, czero, 0, 0, 0);
#pragma unroll
            for (int r = 0; r < 16; ++r) c[r] = __builtin_amdgcn_exp2f(c[r]);

            bf16x8 elo, ehi;
#pragma unroll
            for (int r = 0; r < 8; ++r) { elo[r] = (__bf16)c[r]; ehi[r] = (__bf16)c[r + 8]; }

            const ushort* ap = (l31 == 1) ? ones_lds : (sb + ql + (hi << 3));
            bf16x8 a1 = __builtin_bit_cast(bf16x8, *(const short8v*)ap);
            bf16x8 a2 = __builtin_bit_cast(bf16x8, *(const short8v*)(ap + 16));

            c_pv0 = __builtin_amdgcn_mfma_f32_32x32x16_bf16(a1, elo, c_pv0, 0, 0, 0);
            c_pv1 = __builtin_amdgcn_mfma_f32_32x32x16_bf16(a2, ehi, c_pv1, 0, 0, 0);
        }
        __syncthreads();   // buf consumed; buf^1 + x slice j landed
    }

    // partials: D rows 0 = sum e*s, 1 = sum e (regs 0,1 of hi=0 lanes)
    if (!hi) {
        part_a[qs][pg * 32 + l31] = c_pv0[0] + c_pv1[0];
        part_l[qs][pg * 32 + l31] = c_pv0[1] + c_pv1[1];
    }
    __syncthreads();

    // merge + att_map output
    if (tid < PTILE) {
        float l = (part_l[0][tid] + part_l[1][tid]) + (part_l[2][tid] + part_l[3][tid]);
        float a = (part_a[0][tid] + part_a[1][tid]) + (part_a[2][tid] + part_a[3][tid]);
        float att = a / l;
        att_lds[tid] = att;
        out[(size_t)n * HWP + p0 + tid] = att;
    }
    __syncthreads();

    // epilogue: out = att*gamma + x_tile (LDS) — write-only HBM tail
    const float gm = gamma[0];
    float* outp = out + NHW + (size_t)n * CH * HWP + p0;
#pragma unroll
    for (int it = 0; it < 2; ++it) {
        int idx = it * 512 + tid;      // 1024 float4s over (c, p/4)
        int c   = idx >> 4;
        int p4  = (idx & 15) << 2;
        float4 xv = ((const float4*)x_tile)[idx];
        float4 av = *(const float4*)(att_lds + p4);
        float4 o;
        o.x = fmaf(av.x, gm, xv.x);
        o.y = fmaf(av.y, gm, xv.y);
        o.z = fmaf(av.z, gm, xv.z);
        o.w = fmaf(av.w, gm, xv.w);
        *(float4*)(outp + (size_t)c * HWP + p4) = o;
    }
}

extern "C" void kernel_launch(void* const* d_in, const int* in_sizes, int n_in,
                              void* d_out, int out_size, void* d_ws, size_t ws_size,
                              hipStream_t stream) {
    const float* x     = (const float*)d_in[0];
    const float* Wf    = (const float*)d_in[1];
    const float* bf    = (const float*)d_in[2];
    const float* Wg    = (const float*)d_in[3];
    const float* bg    = (const float*)d_in[4];
    const float* Ws    = (const float*)d_in[5];
    const float* bs    = (const float*)d_in[6];
    const float* gamma = (const float*)d_in[7];
    float* out = (float*)d_out;
    float* ws  = (float*)d_ws;

    // d_out layout: att_map [NB*HWP] then output [NB*CH*HWP]
    proj_kernel<<<NB * (HWP / 128), 128, 0, stream>>>(x, Wf, bf, Wg, bg, Ws, bs, ws);
    attn_finish_kernel<<<NB * (HWP / PTILE), 512, 0, stream>>>(x, gamma, ws, out);
}

// Round 12
// 31.031 us; speedup vs baseline: 1.1858x; 1.1706x over previous
//
#include <hip/hip_runtime.h>

// Problem constants
#define NB 8
#define CH 64
#define KP 8            // K = C/8
#define HWP 4096        // H*W
#define NHW (NB * HWP)  // 32768
#define PTILE 64        // p-rows per attn block
#define QC 512          // q staging chunk
#define NCHUNK (HWP / QC)   // 8

typedef float f32x16 __attribute__((ext_vector_type(16)));
typedef __bf16 bf16x8 __attribute__((ext_vector_type(8)));
typedef short short8v __attribute__((ext_vector_type(8)));

// Workspace layout (float offsets)
#define WS_FB  0                 // f bf16 [NB][HWP][8], pre-scaled by log2(e)
#define WS_GB  (NHW * 4)         // g bf16 [NB][HWP][8]
#define WS_SB  (NHW * 8)         // s bf16 [NB][HWP], pre-shuffled per 16

// s shuffle: within each 16-block, position j holds s[porder[j]],
// porder = {0,1,2,3, 8,9,10,11, 4,5,6,7, 12,13,14,15} (involution).
// Makes PV MFMA A-frag k-order match the e-tile C-reg q-order (verified R6-R11).
__device__ __forceinline__ int s_shuf_idx(int i) {
    return i ^ (((((i >> 2) ^ (i >> 3)) & 1) != 0) ? 12 : 0);
}

// ---------------------------------------------------------------------------
// Kernel 1: 1x1-conv projections — R12 rewrite for occupancy.
// 256 blocks x 512 threads: 128 pixels x 4 channel-quarters. Each thread
// reads only 16 x values (independent loads, coalesced across lanes),
// accumulates 17 partial sums; quarters 1-3 park partials in LDS
// (stride 17 = odd -> bank-conflict-free); quarter 0 reduces and emits
// the exact R5-R11 outputs (bf16 f*L2E, bf16 g, shuffled bf16 s).
// ---------------------------------------------------------------------------
__global__ __launch_bounds__(512) void proj_kernel(
    const float* __restrict__ x,
    const float* __restrict__ Wf, const float* __restrict__ bf,
    const float* __restrict__ Wg, const float* __restrict__ bg,
    const float* __restrict__ Ws, const float* __restrict__ bs,
    float* __restrict__ ws)
{
    __shared__ float part[3][128][17];    // 25.5 KB

    const int blk = blockIdx.x;           // 256 blocks: 32 per batch
    const int n   = blk >> 5;
    const int p0  = (blk & 31) << 7;      // 128 pixels per block
    const int px  = threadIdx.x & 127;
    const int q   = threadIdx.x >> 7;     // c-quarter 0..3 (wave-uniform)
    const int p   = p0 + px;

    const float* xp = x + (size_t)n * CH * HWP + (size_t)(q * 16) * HWP + p;

    float accf[KP], accg[KP], accs;
    if (q == 0) {
#pragma unroll
        for (int k = 0; k < KP; ++k) { accf[k] = bf[k]; accg[k] = bg[k]; }
        accs = bs[0];
    } else {
#pragma unroll
        for (int k = 0; k < KP; ++k) { accf[k] = 0.f; accg[k] = 0.f; }
        accs = 0.f;
    }

#pragma unroll
    for (int c = 0; c < 16; ++c) {        // 16 independent coalesced loads
        float xv = xp[(size_t)c * HWP];
        int cc = q * 16 + c;
#pragma unroll
        for (int k = 0; k < KP; ++k) {
            accf[k] = fmaf(Wf[k * CH + cc], xv, accf[k]);
            accg[k] = fmaf(Wg[k * CH + cc], xv, accg[k]);
        }
        accs = fmaf(Ws[cc], xv, accs);
    }

    if (q != 0) {
        float* dst = part[q - 1][px];
#pragma unroll
        for (int k = 0; k < KP; ++k) { dst[k] = accf[k]; dst[KP + k] = accg[k]; }
        dst[16] = accs;
    }
    __syncthreads();

    if (q == 0) {
#pragma unroll
        for (int j = 0; j < 3; ++j) {
            const float* src = part[j][px];
#pragma unroll
            for (int k = 0; k < KP; ++k) { accf[k] += src[k]; accg[k] += src[KP + k]; }
            accs += src[16];
        }

        const float L2E = 1.4426950408889634f;
        bf16x8 fv, gv;
#pragma unroll
        for (int k = 0; k < KP; ++k) {
            fv[k] = (__bf16)(accf[k] * L2E);
            gv[k] = (__bf16)accg[k];
        }

        ushort* fb = (ushort*)(ws + WS_FB) + (size_t)(n * HWP + p) * 8;
        ushort* gb = (ushort*)(ws + WS_GB) + (size_t)(n * HWP + p) * 8;
        *(short8v*)fb = __builtin_bit_cast(short8v, fv);
        *(short8v*)gb = __builtin_bit_cast(short8v, gv);

        __bf16 sb16 = (__bf16)accs;
        ((ushort*)(ws + WS_SB))[(size_t)n * HWP + (p & ~15) + s_shuf_idx(p & 15)] =
            __builtin_bit_cast(ushort, sb16);
    }
}

// ---------------------------------------------------------------------------
// Kernel 2 (fused attn + merge + epilogue) — byte-identical to R11 (verified
// absmax 0.015625). Block = (n, 64 p), 8 waves (2 pg x 4 qs), 8 double-
// buffered 512-q chunks; x tile staged per-chunk; epilogue from LDS.
// ---------------------------------------------------------------------------
__global__ __launch_bounds__(512, 4) void attn_finish_kernel(
    const float* __restrict__ x, const float* __restrict__ gamma,
    float* __restrict__ ws, float* __restrict__ out)
{
    __shared__ alignas(16) ushort g_lds[2][(QC + 1) * KP];  // 16.4 KB (+zero rows)
    __shared__ alignas(16) ushort s_lds[2][QC];             // 2 KB
    __shared__ alignas(16) float  x_tile[CH * PTILE];       // 16 KB
    __shared__ ushort ones_lds[32];                         // 64 B
    __shared__ float  part_l[4][PTILE];                     // 1 KB
    __shared__ float  part_a[4][PTILE];                     // 1 KB
    __shared__ float  att_lds[PTILE];                       // 256 B

    const int blk  = blockIdx.x;       // 512 = n(8) * ptile(64)
    const int n    = blk >> 6;
    const int p0   = (blk & 63) << 6;
    const int tid  = threadIdx.x;
    const int lane = tid & 63;
    const int w    = tid >> 6;         // 0..7
    const int pg   = w & 1;            // p-group (32 rows)
    const int qs   = w >> 1;           // q-split 0..3
    const int l31  = lane & 31;
    const int hi   = lane >> 5;

    if (tid < 16) ((uint*)ones_lds)[tid] = 0x3F803F80u;     // bf16 1.0 pairs
    if (tid < 8) { g_lds[0][QC * KP + tid] = 0; g_lds[1][QC * KP + tid] = 0; }

    // B-fragment: f rows for this wave's 32 p (lanes 0-31 real)
    const ushort* fbase = (const ushort*)(ws + WS_FB) + (size_t)n * HWP * KP;
    short8v z8 = {0, 0, 0, 0, 0, 0, 0, 0};
    bf16x8 bfrag = __builtin_bit_cast(bf16x8,
        hi ? z8 : *(const short8v*)(fbase + (size_t)(p0 + pg * 32 + l31) * KP));

    const float4* gsrc = (const float4*)((const ushort*)(ws + WS_GB) +
                                         (size_t)n * HWP * KP);
    const float4* ssrc = (const float4*)((const ushort*)(ws + WS_SB) +
                                         (size_t)n * HWP);
    const float* xn = x + (size_t)n * CH * HWP + p0;

    const f32x16 czero = {0.f};
    f32x16 c_pv0 = {0.f};
    f32x16 c_pv1 = {0.f};

    // stage chunk 0
    ((float4*)g_lds[0])[tid] = gsrc[tid];
    if (tid < QC / 8) ((float4*)s_lds[0])[tid] = ssrc[tid];
    __syncthreads();

#pragma unroll 1
    for (int j = 0; j < NCHUNK; ++j) {
        const int buf = j & 1;
        if (j + 1 < NCHUNK) {          // prefetch next g/s chunk into other buffer
            ((float4*)g_lds[buf ^ 1])[tid] = gsrc[(j + 1) * QC + tid];
            if (tid < QC / 8)
                ((float4*)s_lds[buf ^ 1])[tid] = ssrc[(j + 1) * (QC / 8) + tid];
        }
        // x-tile slice j (2 KB) rides the same async-stage window (T14).
        if (tid < 128) {
            int f = (j << 7) + tid;
            ((float4*)x_tile)[f] =
                *(const float4*)(xn + (size_t)(f >> 4) * HWP + ((f & 15) << 2));
        }
        const ushort* gb = g_lds[buf];
        const ushort* sb = s_lds[buf];

#pragma unroll 1
        for (int t = 0; t < 4; ++t) {
            const int ql = qs * 128 + t * 32;    // q offset within chunk
            int arow = hi ? QC : (ql + l31);
            bf16x8 afrag = __builtin_bit_cast(bf16x8,
                *(const short8v*)(gb + (size_t)arow * KP));

            f32x16 c = __builtin_amdgcn_mfma_f32_32x32x16_bf16(
                afrag, bfrag, czero, 0, 0, 0);
#pragma unroll
            for (int r = 0; r < 16; ++r) c[r] = __builtin_amdgcn_exp2f(c[r]);

            bf16x8 elo, ehi;
#pragma unroll
            for (int r = 0; r < 8; ++r) { elo[r] = (__bf16)c[r]; ehi[r] = (__bf16)c[r + 8]; }

            const ushort* ap = (l31 == 1) ? ones_lds : (sb + ql + (hi << 3));
            bf16x8 a1 = __builtin_bit_cast(bf16x8, *(const short8v*)ap);
            bf16x8 a2 = __builtin_bit_cast(bf16x8, *(const short8v*)(ap + 16));

            c_pv0 = __builtin_amdgcn_mfma_f32_32x32x16_bf16(a1, elo, c_pv0, 0, 0, 0);
            c_pv1 = __builtin_amdgcn_mfma_f32_32x32x16_bf16(a2, ehi, c_pv1, 0, 0, 0);
        }
        __syncthreads();   // buf consumed; buf^1 + x slice j landed
    }

    // partials: D rows 0 = sum e*s, 1 = sum e (regs 0,1 of hi=0 lanes)
    if (!hi) {
        part_a[qs][pg * 32 + l31] = c_pv0[0] + c_pv1[0];
        part_l[qs][pg * 32 + l31] = c_pv0[1] + c_pv1[1];
    }
    __syncthreads();

    // merge + att_map output
    if (tid < PTILE) {
        float l = (part_l[0][tid] + part_l[1][tid]) + (part_l[2][tid] + part_l[3][tid]);
        float a = (part_a[0][tid] + part_a[1][tid]) + (part_a[2][tid] + part_a[3][tid]);
        float att = a / l;
        att_lds[tid] = att;
        out[(size_t)n * HWP + p0 + tid] = att;
    }
    __syncthreads();

    // epilogue: out = att*gamma + x_tile (LDS) — write-only HBM tail
    const float gm = gamma[0];
    float* outp = out + NHW + (size_t)n * CH * HWP + p0;
#pragma unroll
    for (int it = 0; it < 2; ++it) {
        int idx = it * 512 + tid;      // 1024 float4s over (c, p/4)
        int c   = idx >> 4;
        int p4  = (idx & 15) << 2;
        float4 xv = ((const float4*)x_tile)[idx];
        float4 av = *(const float4*)(att_lds + p4);
        float4 o;
        o.x = fmaf(av.x, gm, xv.x);
        o.y = fmaf(av.y, gm, xv.y);
        o.z = fmaf(av.z, gm, xv.z);
        o.w = fmaf(av.w, gm, xv.w);
        *(float4*)(outp + (size_t)c * HWP + p4) = o;
    }
}

extern "C" void kernel_launch(void* const* d_in, const int* in_sizes, int n_in,
                              void* d_out, int out_size, void* d_ws, size_t ws_size,
                              hipStream_t stream) {
    const float* x     = (const float*)d_in[0];
    const float* Wf    = (const float*)d_in[1];
    const float* bf    = (const float*)d_in[2];
    const float* Wg    = (const float*)d_in[3];
    const float* bg    = (const float*)d_in[4];
    const float* Ws    = (const float*)d_in[5];
    const float* bs    = (const float*)d_in[6];
    const float* gamma = (const float*)d_in[7];
    float* out = (float*)d_out;
    float* ws  = (float*)d_ws;

    // d_out layout: att_map [NB*HWP] then output [NB*CH*HWP]
    proj_kernel<<<NB * (HWP / 128), 512, 0, stream>>>(x, Wf, bf, Wg, bg, Ws, bs, ws);
    attn_finish_kernel<<<NB * (HWP / PTILE), 512, 0, stream>>>(x, gamma, ws, out);
}

// Round 13
// 30.577 us; speedup vs baseline: 1.2034x; 1.0149x over previous
//
#include <hip/hip_runtime.h>

// Problem constants
#define NB 8
#define CH 64
#define KP 8            // K = C/8
#define HWP 4096        // H*W
#define NHW (NB * HWP)  // 32768
#define PTILE 64        // p-rows per attn block
#define QC 512          // q staging chunk
#define NCHUNK (HWP / QC)   // 8

typedef float f32x16 __attribute__((ext_vector_type(16)));
typedef __bf16 bf16x8 __attribute__((ext_vector_type(8)));
typedef short short8v __attribute__((ext_vector_type(8)));

// Workspace layout (float offsets)
#define WS_FB  0                 // f bf16 [NB][HWP][8], pre-scaled by log2(e)
#define WS_GB  (NHW * 4)         // g bf16 [NB][HWP][8]
#define WS_SB  (NHW * 8)         // s bf16 [NB][HWP], pre-shuffled per 16

// s shuffle: within each 16-block, position j holds s[porder[j]],
// porder = {0,1,2,3, 8,9,10,11, 4,5,6,7, 12,13,14,15} (involution).
// Makes PV MFMA A-frag k-order match the e-tile C-reg q-order (verified R6-R12).
__device__ __forceinline__ int s_shuf_idx(int i) {
    return i ^ (((((i >> 2) ^ (i >> 3)) & 1) != 0) ? 12 : 0);
}

// ---------------------------------------------------------------------------
// Kernel 1: 1x1-conv projections — R12-verified (4-way channel split,
// 2048 waves, 16 loads/thread, LDS reduce).
// ---------------------------------------------------------------------------
__global__ __launch_bounds__(512) void proj_kernel(
    const float* __restrict__ x,
    const float* __restrict__ Wf, const float* __restrict__ bf,
    const float* __restrict__ Wg, const float* __restrict__ bg,
    const float* __restrict__ Ws, const float* __restrict__ bs,
    float* __restrict__ ws)
{
    __shared__ float part[3][128][17];    // 25.5 KB

    const int blk = blockIdx.x;           // 256 blocks: 32 per batch
    const int n   = blk >> 5;
    const int p0  = (blk & 31) << 7;      // 128 pixels per block
    const int px  = threadIdx.x & 127;
    const int q   = threadIdx.x >> 7;     // c-quarter 0..3 (wave-uniform)
    const int p   = p0 + px;

    const float* xp = x + (size_t)n * CH * HWP + (size_t)(q * 16) * HWP + p;

    float accf[KP], accg[KP], accs;
    if (q == 0) {
#pragma unroll
        for (int k = 0; k < KP; ++k) { accf[k] = bf[k]; accg[k] = bg[k]; }
        accs = bs[0];
    } else {
#pragma unroll
        for (int k = 0; k < KP; ++k) { accf[k] = 0.f; accg[k] = 0.f; }
        accs = 0.f;
    }

#pragma unroll
    for (int c = 0; c < 16; ++c) {        // 16 independent coalesced loads
        float xv = xp[(size_t)c * HWP];
        int cc = q * 16 + c;
#pragma unroll
        for (int k = 0; k < KP; ++k) {
            accf[k] = fmaf(Wf[k * CH + cc], xv, accf[k]);
            accg[k] = fmaf(Wg[k * CH + cc], xv, accg[k]);
        }
        accs = fmaf(Ws[cc], xv, accs);
    }

    if (q != 0) {
        float* dst = part[q - 1][px];
#pragma unroll
        for (int k = 0; k < KP; ++k) { dst[k] = accf[k]; dst[KP + k] = accg[k]; }
        dst[16] = accs;
    }
    __syncthreads();

    if (q == 0) {
#pragma unroll
        for (int j = 0; j < 3; ++j) {
            const float* src = part[j][px];
#pragma unroll
            for (int k = 0; k < KP; ++k) { accf[k] += src[k]; accg[k] += src[KP + k]; }
            accs += src[16];
        }

        const float L2E = 1.4426950408889634f;
        bf16x8 fv, gv;
#pragma unroll
        for (int k = 0; k < KP; ++k) {
            fv[k] = (__bf16)(accf[k] * L2E);
            gv[k] = (__bf16)accg[k];
        }

        ushort* fb = (ushort*)(ws + WS_FB) + (size_t)(n * HWP + p) * 8;
        ushort* gb = (ushort*)(ws + WS_GB) + (size_t)(n * HWP + p) * 8;
        *(short8v*)fb = __builtin_bit_cast(short8v, fv);
        *(short8v*)gb = __builtin_bit_cast(short8v, gv);

        __bf16 sb16 = (__bf16)accs;
        ((ushort*)(ws + WS_SB))[(size_t)n * HWP + (p & ~15) + s_shuf_idx(p & 15)] =
            __builtin_bit_cast(ushort, sb16);
    }
}

// ---------------------------------------------------------------------------
// Kernel 2 (fused attn + merge + epilogue). R13: VGPR diet for 8 waves/SIMD —
// SINGLE chained PV accumulator (-16 VGPR), x_tile staging dropped (x is
// L3-resident; R11 showed staging is worthless), __launch_bounds__(512,8)
// caps VGPR at 64 (4 blocks/CU, LDS 21KB*4=83KB). Tile math verified R6-R12.
// ---------------------------------------------------------------------------
__global__ __launch_bounds__(512, 8) void attn_finish_kernel(
    const float* __restrict__ x, const float* __restrict__ gamma,
    float* __restrict__ ws, float* __restrict__ out)
{
    __shared__ alignas(16) ushort g_lds[2][(QC + 1) * KP];  // 16.4 KB (+zero rows)
    __shared__ alignas(16) ushort s_lds[2][QC];             // 2 KB
    __shared__ ushort ones_lds[32];                         // 64 B
    __shared__ float  part_l[4][PTILE];                     // 1 KB
    __shared__ float  part_a[4][PTILE];                     // 1 KB
    __shared__ float  att_lds[PTILE];                       // 256 B

    const int blk  = blockIdx.x;       // 512 = n(8) * ptile(64)
    const int n    = blk >> 6;
    const int p0   = (blk & 63) << 6;
    const int tid  = threadIdx.x;
    const int lane = tid & 63;
    const int w    = tid >> 6;         // 0..7
    const int pg   = w & 1;            // p-group (32 rows)
    const int qs   = w >> 1;           // q-split 0..3
    const int l31  = lane & 31;
    const int hi   = lane >> 5;

    if (tid < 16) ((uint*)ones_lds)[tid] = 0x3F803F80u;     // bf16 1.0 pairs
    if (tid < 8) { g_lds[0][QC * KP + tid] = 0; g_lds[1][QC * KP + tid] = 0; }

    // B-fragment: f rows for this wave's 32 p (lanes 0-31 real)
    const ushort* fbase = (const ushort*)(ws + WS_FB) + (size_t)n * HWP * KP;
    short8v z8 = {0, 0, 0, 0, 0, 0, 0, 0};
    bf16x8 bfrag = __builtin_bit_cast(bf16x8,
        hi ? z8 : *(const short8v*)(fbase + (size_t)(p0 + pg * 32 + l31) * KP));

    const float4* gsrc = (const float4*)((const ushort*)(ws + WS_GB) +
                                         (size_t)n * HWP * KP);
    const float4* ssrc = (const float4*)((const ushort*)(ws + WS_SB) +
                                         (size_t)n * HWP);

    const f32x16 czero = {0.f};
    f32x16 c_pv = {0.f};

    // stage chunk 0
    ((float4*)g_lds[0])[tid] = gsrc[tid];
    if (tid < QC / 8) ((float4*)s_lds[0])[tid] = ssrc[tid];
    __syncthreads();

#pragma unroll 1
    for (int j = 0; j < NCHUNK; ++j) {
        const int buf = j & 1;
        if (j + 1 < NCHUNK) {          // prefetch next g/s chunk into other buffer
            ((float4*)g_lds[buf ^ 1])[tid] = gsrc[(j + 1) * QC + tid];
            if (tid < QC / 8)
                ((float4*)s_lds[buf ^ 1])[tid] = ssrc[(j + 1) * (QC / 8) + tid];
        }
        const ushort* gb = g_lds[buf];
        const ushort* sb = s_lds[buf];

#pragma unroll 1
        for (int t = 0; t < 4; ++t) {
            const int ql = qs * 128 + t * 32;    // q offset within chunk
            int arow = hi ? QC : (ql + l31);
            bf16x8 afrag = __builtin_bit_cast(bf16x8,
                *(const short8v*)(gb + (size_t)arow * KP));

            f32x16 c = __builtin_amdgcn_mfma_f32_32x32x16_bf16(
                afrag, bfrag, czero, 0, 0, 0);
#pragma unroll
            for (int r = 0; r < 16; ++r) c[r] = __builtin_amdgcn_exp2f(c[r]);

            bf16x8 elo, ehi;
#pragma unroll
            for (int r = 0; r < 8; ++r) { elo[r] = (__bf16)c[r]; ehi[r] = (__bf16)c[r + 8]; }

            const ushort* ap = (l31 == 1) ? ones_lds : (sb + ql + (hi << 3));
            bf16x8 a1 = __builtin_bit_cast(bf16x8, *(const short8v*)ap);
            bf16x8 a2 = __builtin_bit_cast(bf16x8, *(const short8v*)(ap + 16));

            c_pv = __builtin_amdgcn_mfma_f32_32x32x16_bf16(a1, elo, c_pv, 0, 0, 0);
            c_pv = __builtin_amdgcn_mfma_f32_32x32x16_bf16(a2, ehi, c_pv, 0, 0, 0);
        }
        __syncthreads();   // buf consumed; buf^1 staged
    }

    // partials: D rows 0 = sum e*s, 1 = sum e (regs 0,1 of hi=0 lanes)
    if (!hi) {
        part_a[qs][pg * 32 + l31] = c_pv[0];
        part_l[qs][pg * 32 + l31] = c_pv[1];
    }
    __syncthreads();

    // merge + att_map output
    if (tid < PTILE) {
        float l = (part_l[0][tid] + part_l[1][tid]) + (part_l[2][tid] + part_l[3][tid]);
        float a = (part_a[0][tid] + part_a[1][tid]) + (part_a[2][tid] + part_a[3][tid]);
        float att = a / l;
        att_lds[tid] = att;
        out[(size_t)n * HWP + p0 + tid] = att;
    }
    __syncthreads();

    // epilogue: out = att*gamma + x (x is L3-resident after proj's read)
    const float gm = gamma[0];
    const float* xn = x + (size_t)n * CH * HWP + p0;
    float* outp = out + NHW + (size_t)n * CH * HWP + p0;
#pragma unroll
    for (int it = 0; it < 2; ++it) {
        int idx = it * 512 + tid;      // 1024 float4s over (c, p/4)
        int c   = idx >> 4;
        int p4  = (idx & 15) << 2;
        float4 xv = *(const float4*)(xn + (size_t)c * HWP + p4);
        float4 av = *(const float4*)(att_lds + p4);
        float4 o;
        o.x = fmaf(av.x, gm, xv.x);
        o.y = fmaf(av.y, gm, xv.y);
        o.z = fmaf(av.z, gm, xv.z);
        o.w = fmaf(av.w, gm, xv.w);
        *(float4*)(outp + (size_t)c * HWP + p4) = o;
    }
}

extern "C" void kernel_launch(void* const* d_in, const int* in_sizes, int n_in,
                              void* d_out, int out_size, void* d_ws, size_t ws_size,
                              hipStream_t stream) {
    const float* x     = (const float*)d_in[0];
    const float* Wf    = (const float*)d_in[1];
    const float* bf    = (const float*)d_in[2];
    const float* Wg    = (const float*)d_in[3];
    const float* bg    = (const float*)d_in[4];
    const float* Ws    = (const float*)d_in[5];
    const float* bs    = (const float*)d_in[6];
    const float* gamma = (const float*)d_in[7];
    float* out = (float*)d_out;
    float* ws  = (float*)d_ws;

    // d_out layout: att_map [NB*HWP] then output [NB*CH*HWP]
    proj_kernel<<<NB * (HWP / 128), 512, 0, stream>>>(x, Wf, bf, Wg, bg, Ws, bs, ws);
    attn_finish_kernel<<<NB * (HWP / PTILE), 512, 0, stream>>>(x, gamma, ws, out);
}

// Round 14
// 30.284 us; speedup vs baseline: 1.2150x; 1.0097x over previous
//
#include <hip/hip_runtime.h>

// Problem constants
#define NB 8
#define CH 64
#define KP 8            // K = C/8
#define HWP 4096        // H*W
#define NHW (NB * HWP)  // 32768
#define PTILE 64        // p-rows per attn block

typedef float f32x16 __attribute__((ext_vector_type(16)));
typedef __bf16 bf16x8 __attribute__((ext_vector_type(8)));
typedef short short8v __attribute__((ext_vector_type(8)));

// Workspace layout (float offsets)
#define WS_FB  0                 // f bf16 [NB][HWP][8], pre-scaled by log2(e)
#define WS_GB  (NHW * 4)         // g bf16 [NB][HWP][8]
#define WS_SB  (NHW * 8)         // s bf16 [NB][HWP], pre-shuffled per 16

// s shuffle: within each 16-block, position j holds s[porder[j]],
// porder = {0,1,2,3, 8,9,10,11, 4,5,6,7, 12,13,14,15} (involution).
// Makes PV MFMA A-frag k-order match the e-tile C-reg q-order (verified R6-R13).
__device__ __forceinline__ int s_shuf_idx(int i) {
    return i ^ (((((i >> 2) ^ (i >> 3)) & 1) != 0) ? 12 : 0);
}

// ---------------------------------------------------------------------------
// Kernel 1: 1x1-conv projections — R12-verified (4-way channel split).
// ---------------------------------------------------------------------------
__global__ __launch_bounds__(512) void proj_kernel(
    const float* __restrict__ x,
    const float* __restrict__ Wf, const float* __restrict__ bf,
    const float* __restrict__ Wg, const float* __restrict__ bg,
    const float* __restrict__ Ws, const float* __restrict__ bs,
    float* __restrict__ ws)
{
    __shared__ float part[3][128][17];    // 25.5 KB

    const int blk = blockIdx.x;           // 256 blocks: 32 per batch
    const int n   = blk >> 5;
    const int p0  = (blk & 31) << 7;      // 128 pixels per block
    const int px  = threadIdx.x & 127;
    const int q   = threadIdx.x >> 7;     // c-quarter 0..3 (wave-uniform)
    const int p   = p0 + px;

    const float* xp = x + (size_t)n * CH * HWP + (size_t)(q * 16) * HWP + p;

    float accf[KP], accg[KP], accs;
    if (q == 0) {
#pragma unroll
        for (int k = 0; k < KP; ++k) { accf[k] = bf[k]; accg[k] = bg[k]; }
        accs = bs[0];
    } else {
#pragma unroll
        for (int k = 0; k < KP; ++k) { accf[k] = 0.f; accg[k] = 0.f; }
        accs = 0.f;
    }

#pragma unroll
    for (int c = 0; c < 16; ++c) {        // 16 independent coalesced loads
        float xv = xp[(size_t)c * HWP];
        int cc = q * 16 + c;
#pragma unroll
        for (int k = 0; k < KP; ++k) {
            accf[k] = fmaf(Wf[k * CH + cc], xv, accf[k]);
            accg[k] = fmaf(Wg[k * CH + cc], xv, accg[k]);
        }
        accs = fmaf(Ws[cc], xv, accs);
    }

    if (q != 0) {
        float* dst = part[q - 1][px];
#pragma unroll
        for (int k = 0; k < KP; ++k) { dst[k] = accf[k]; dst[KP + k] = accg[k]; }
        dst[16] = accs;
    }
    __syncthreads();

    if (q == 0) {
#pragma unroll
        for (int j = 0; j < 3; ++j) {
            const float* src = part[j][px];
#pragma unroll
            for (int k = 0; k < KP; ++k) { accf[k] += src[k]; accg[k] += src[KP + k]; }
            accs += src[16];
        }

        const float L2E = 1.4426950408889634f;
        bf16x8 fv, gv;
#pragma unroll
        for (int k = 0; k < KP; ++k) {
            fv[k] = (__bf16)(accf[k] * L2E);
            gv[k] = (__bf16)accg[k];
        }

        ushort* fb = (ushort*)(ws + WS_FB) + (size_t)(n * HWP + p) * 8;
        ushort* gb = (ushort*)(ws + WS_GB) + (size_t)(n * HWP + p) * 8;
        *(short8v*)fb = __builtin_bit_cast(short8v, fv);
        *(short8v*)gb = __builtin_bit_cast(short8v, gv);

        __bf16 sb16 = (__bf16)accs;
        ((ushort*)(ws + WS_SB))[(size_t)n * HWP + (p & ~15) + s_shuf_idx(p & 15)] =
            __builtin_bit_cast(ushort, sb16);
    }
}

// ---------------------------------------------------------------------------
// Kernel 2 (fused attn + merge + epilogue). R14: BARRIER-FREE sweep.
// g is L2-resident (2 MB total) — read per-tile directly from global
// (Common-mistake #7: don't LDS-stage cache-fit data); s staged once (8 KB).
// Only 2 barriers in the whole kernel. Each of the 8 waves sweeps its
// 1024-q range independently; one-tile g prefetch hides L2 latency.
// Tile math byte-identical to R6-R13 (absmax 0.015625).
// ---------------------------------------------------------------------------
__global__ __launch_bounds__(512, 8) void attn_finish_kernel(
    const float* __restrict__ x, const float* __restrict__ gamma,
    float* __restrict__ ws, float* __restrict__ out)
{
    __shared__ alignas(16) ushort s_lds[HWP];   // 8 KB: whole shuffled s row
    __shared__ ushort ones_lds[32];             // 64 B
    __shared__ float  part_l[4][PTILE];         // 1 KB
    __shared__ float  part_a[4][PTILE];         // 1 KB
    __shared__ float  att_lds[PTILE];           // 256 B

    const int blk  = blockIdx.x;       // 512 = n(8) * ptile(64)
    const int n    = blk >> 6;
    const int p0   = (blk & 63) << 6;
    const int tid  = threadIdx.x;
    const int lane = tid & 63;
    const int w    = tid >> 6;         // 0..7
    const int pg   = w & 1;            // p-group (32 rows)
    const int qs   = w >> 1;           // q-split 0..3 (1024 q each)
    const int l31  = lane & 31;
    const int hi   = lane >> 5;

    // stage whole s row (4096 bf16 = 512 float4s = 1/thread) + ones
    ((float4*)s_lds)[tid] =
        ((const float4*)((const ushort*)(ws + WS_SB) + (size_t)n * HWP))[tid];
    if (tid < 16) ((uint*)ones_lds)[tid] = 0x3F803F80u;

    // B-fragment: f rows for this wave's 32 p (lanes 0-31 real)
    const ushort* fbase = (const ushort*)(ws + WS_FB) + (size_t)n * HWP * KP;
    short8v z8 = {0, 0, 0, 0, 0, 0, 0, 0};
    bf16x8 bfrag = __builtin_bit_cast(bf16x8,
        hi ? z8 : *(const short8v*)(fbase + (size_t)(p0 + pg * 32 + l31) * KP));

    const ushort* gbase = (const ushort*)(ws + WS_GB) + (size_t)n * HWP * KP;

    __syncthreads();    // s_lds ready — last barrier until merge

    const f32x16 czero = {0.f};
    f32x16 c_pv = {0.f};

    const int qw = qs << 10;           // wave's q range start
    // prefetch tile 0's g row (lanes 0-31; hi lanes use zero frag)
    short8v araw = z8;
    if (!hi) araw = *(const short8v*)(gbase + (size_t)(qw + l31) * KP);

#pragma unroll 1
    for (int t = 0; t < 32; ++t) {     // 32 tiles of 32 q
        bf16x8 afrag = __builtin_bit_cast(bf16x8, araw);
        // prefetch next tile's g row (L2-hit, hides under exp2/cvt)
        if (t + 1 < 32 && !hi)
            araw = *(const short8v*)(gbase + (size_t)(qw + (t + 1) * 32 + l31) * KP);

        f32x16 c = __builtin_amdgcn_mfma_f32_32x32x16_bf16(
            afrag, bfrag, czero, 0, 0, 0);
#pragma unroll
        for (int r = 0; r < 16; ++r) c[r] = __builtin_amdgcn_exp2f(c[r]);

        bf16x8 elo, ehi;
#pragma unroll
        for (int r = 0; r < 8; ++r) { elo[r] = (__bf16)c[r]; ehi[r] = (__bf16)c[r + 8]; }

        const int qbase = qw + (t << 5);
        const ushort* ap = (l31 == 1) ? ones_lds : (s_lds + qbase + (hi << 3));
        bf16x8 a1 = __builtin_bit_cast(bf16x8, *(const short8v*)ap);
        bf16x8 a2 = __builtin_bit_cast(bf16x8, *(const short8v*)(ap + 16));

        c_pv = __builtin_amdgcn_mfma_f32_32x32x16_bf16(a1, elo, c_pv, 0, 0, 0);
        c_pv = __builtin_amdgcn_mfma_f32_32x32x16_bf16(a2, ehi, c_pv, 0, 0, 0);
    }

    // partials: D rows 0 = sum e*s, 1 = sum e (regs 0,1 of hi=0 lanes)
    if (!hi) {
        part_a[qs][pg * 32 + l31] = c_pv[0];
        part_l[qs][pg * 32 + l31] = c_pv[1];
    }
    __syncthreads();

    // merge + att_map output
    if (tid < PTILE) {
        float l = (part_l[0][tid] + part_l[1][tid]) + (part_l[2][tid] + part_l[3][tid]);
        float a = (part_a[0][tid] + part_a[1][tid]) + (part_a[2][tid] + part_a[3][tid]);
        float att = a / l;
        att_lds[tid] = att;
        out[(size_t)n * HWP + p0 + tid] = att;
    }
    __syncthreads();

    // epilogue: out = att*gamma + x (x is L3-resident after proj's read)
    const float gm = gamma[0];
    const float* xn = x + (size_t)n * CH * HWP + p0;
    float* outp = out + NHW + (size_t)n * CH * HWP + p0;
#pragma unroll
    for (int it = 0; it < 2; ++it) {
        int idx = it * 512 + tid;      // 1024 float4s over (c, p/4)
        int c   = idx >> 4;
        int p4  = (idx & 15) << 2;
        float4 xv = *(const float4*)(xn + (size_t)c * HWP + p4);
        float4 av = *(const float4*)(att_lds + p4);
        float4 o;
        o.x = fmaf(av.x, gm, xv.x);
        o.y = fmaf(av.y, gm, xv.y);
        o.z = fmaf(av.z, gm, xv.z);
        o.w = fmaf(av.w, gm, xv.w);
        *(float4*)(outp + (size_t)c * HWP + p4) = o;
    }
}

extern "C" void kernel_launch(void* const* d_in, const int* in_sizes, int n_in,
                              void* d_out, int out_size, void* d_ws, size_t ws_size,
                              hipStream_t stream) {
    const float* x     = (const float*)d_in[0];
    const float* Wf    = (const float*)d_in[1];
    const float* bf    = (const float*)d_in[2];
    const float* Wg    = (const float*)d_in[3];
    const float* bg    = (const float*)d_in[4];
    const float* Ws    = (const float*)d_in[5];
    const float* bs    = (const float*)d_in[6];
    const float* gamma = (const float*)d_in[7];
    float* out = (float*)d_out;
    float* ws  = (float*)d_ws;

    // d_out layout: att_map [NB*HWP] then output [NB*CH*HWP]
    proj_kernel<<<NB * (HWP / 128), 512, 0, stream>>>(x, Wf, bf, Wg, bg, Ws, bs, ws);
    attn_finish_kernel<<<NB * (HWP / PTILE), 512, 0, stream>>>(x, gamma, ws, out);
}

// Round 15
// 29.150 us; speedup vs baseline: 1.2623x; 1.0389x over previous
//
#include <hip/hip_runtime.h>

// Problem constants
#define NB 8
#define CH 64
#define KP 8            // K = C/8
#define HWP 4096        // H*W
#define NHW (NB * HWP)  // 32768
#define PTILE 32        // p-rows per attn block (R15: 64->32 for occupancy)

typedef float f32x16 __attribute__((ext_vector_type(16)));
typedef __bf16 bf16x8 __attribute__((ext_vector_type(8)));
typedef short short8v __attribute__((ext_vector_type(8)));

// Workspace layout (float offsets)
#define WS_FB  0                 // f bf16 [NB][HWP][8], pre-scaled by log2(e)
#define WS_GB  (NHW * 4)         // g bf16 [NB][HWP][8]
#define WS_SB  (NHW * 8)         // s bf16 [NB][HWP], pre-shuffled per 16

// s shuffle: within each 16-block, position j holds s[porder[j]],
// porder = {0,1,2,3, 8,9,10,11, 4,5,6,7, 12,13,14,15} (involution).
// Makes PV MFMA A-frag k-order match the e-tile C-reg q-order (verified R6-R14).
__device__ __forceinline__ int s_shuf_idx(int i) {
    return i ^ (((((i >> 2) ^ (i >> 3)) & 1) != 0) ? 12 : 0);
}

// ---------------------------------------------------------------------------
// Kernel 1: 1x1-conv projections — R12-verified (4-way channel split).
// HBM-bound: reads x (33.5 MB) once, ~6 us floor.
// ---------------------------------------------------------------------------
__global__ __launch_bounds__(512) void proj_kernel(
    const float* __restrict__ x,
    const float* __restrict__ Wf, const float* __restrict__ bf,
    const float* __restrict__ Wg, const float* __restrict__ bg,
    const float* __restrict__ Ws, const float* __restrict__ bs,
    float* __restrict__ ws)
{
    __shared__ float part[3][128][17];    // 25.5 KB

    const int blk = blockIdx.x;           // 256 blocks: 32 per batch
    const int n   = blk >> 5;
    const int p0  = (blk & 31) << 7;      // 128 pixels per block
    const int px  = threadIdx.x & 127;
    const int q   = threadIdx.x >> 7;     // c-quarter 0..3 (wave-uniform)
    const int p   = p0 + px;

    const float* xp = x + (size_t)n * CH * HWP + (size_t)(q * 16) * HWP + p;

    float accf[KP], accg[KP], accs;
    if (q == 0) {
#pragma unroll
        for (int k = 0; k < KP; ++k) { accf[k] = bf[k]; accg[k] = bg[k]; }
        accs = bs[0];
    } else {
#pragma unroll
        for (int k = 0; k < KP; ++k) { accf[k] = 0.f; accg[k] = 0.f; }
        accs = 0.f;
    }

#pragma unroll
    for (int c = 0; c < 16; ++c) {        // 16 independent coalesced loads
        float xv = xp[(size_t)c * HWP];
        int cc = q * 16 + c;
#pragma unroll
        for (int k = 0; k < KP; ++k) {
            accf[k] = fmaf(Wf[k * CH + cc], xv, accf[k]);
            accg[k] = fmaf(Wg[k * CH + cc], xv, accg[k]);
        }
        accs = fmaf(Ws[cc], xv, accs);
    }

    if (q != 0) {
        float* dst = part[q - 1][px];
#pragma unroll
        for (int k = 0; k < KP; ++k) { dst[k] = accf[k]; dst[KP + k] = accg[k]; }
        dst[16] = accs;
    }
    __syncthreads();

    if (q == 0) {
#pragma unroll
        for (int j = 0; j < 3; ++j) {
            const float* src = part[j][px];
#pragma unroll
            for (int k = 0; k < KP; ++k) { accf[k] += src[k]; accg[k] += src[KP + k]; }
            accs += src[16];
        }

        const float L2E = 1.4426950408889634f;
        bf16x8 fv, gv;
#pragma unroll
        for (int k = 0; k < KP; ++k) {
            fv[k] = (__bf16)(accf[k] * L2E);
            gv[k] = (__bf16)accg[k];
        }

        ushort* fb = (ushort*)(ws + WS_FB) + (size_t)(n * HWP + p) * 8;
        ushort* gb = (ushort*)(ws + WS_GB) + (size_t)(n * HWP + p) * 8;
        *(short8v*)fb = __builtin_bit_cast(short8v, fv);
        *(short8v*)gb = __builtin_bit_cast(short8v, gv);

        __bf16 sb16 = (__bf16)accs;
        ((ushort*)(ws + WS_SB))[(size_t)n * HWP + (p & ~15) + s_shuf_idx(p & 15)] =
            __builtin_bit_cast(ushort, sb16);
    }
}

// ---------------------------------------------------------------------------
// Kernel 2 (fused attn + merge + epilogue). R15: PTILE=32 -> 1024 blocks
// (4/CU, 8 waves/SIMD resident), 8 waves = 8 q-splits x 512 q (16 tiles/wave,
// half the serial chain). Barrier-free sweep (R14): g direct from L2, s
// staged once. Tile math byte-identical to R6-R14.
// ---------------------------------------------------------------------------
__global__ __launch_bounds__(512, 8) void attn_finish_kernel(
    const float* __restrict__ x, const float* __restrict__ gamma,
    float* __restrict__ ws, float* __restrict__ out)
{
    __shared__ alignas(16) ushort s_lds[HWP];   // 8 KB: whole shuffled s row
    __shared__ ushort ones_lds[32];             // 64 B
    __shared__ float  part_l[8][PTILE];         // 1 KB
    __shared__ float  part_a[8][PTILE];         // 1 KB
    __shared__ float  att_lds[PTILE];           // 128 B

    const int blk  = blockIdx.x;       // 1024 = n(8) * ptile(128)
    const int n    = blk >> 7;
    const int p0   = (blk & 127) << 5;
    const int tid  = threadIdx.x;
    const int lane = tid & 63;
    const int w    = tid >> 6;         // 0..7 = q-split (512 q each)
    const int l31  = lane & 31;
    const int hi   = lane >> 5;

    // stage whole s row (4096 bf16 = 512 float4s = 1/thread) + ones
    ((float4*)s_lds)[tid] =
        ((const float4*)((const ushort*)(ws + WS_SB) + (size_t)n * HWP))[tid];
    if (tid < 16) ((uint*)ones_lds)[tid] = 0x3F803F80u;

    // B-fragment: f rows for this block's 32 p (lanes 0-31 real)
    const ushort* fbase = (const ushort*)(ws + WS_FB) + (size_t)n * HWP * KP;
    short8v z8 = {0, 0, 0, 0, 0, 0, 0, 0};
    bf16x8 bfrag = __builtin_bit_cast(bf16x8,
        hi ? z8 : *(const short8v*)(fbase + (size_t)(p0 + l31) * KP));

    const ushort* gbase = (const ushort*)(ws + WS_GB) + (size_t)n * HWP * KP;

    __syncthreads();    // s_lds ready — last barrier until merge

    const f32x16 czero = {0.f};
    f32x16 c_pv = {0.f};

    const int qw = w << 9;             // wave's q range start (512 q)
    // prefetch tile 0's g row (lanes 0-31; hi lanes use zero frag)
    short8v araw = z8;
    if (!hi) araw = *(const short8v*)(gbase + (size_t)(qw + l31) * KP);

#pragma unroll 1
    for (int t = 0; t < 16; ++t) {     // 16 tiles of 32 q
        bf16x8 afrag = __builtin_bit_cast(bf16x8, araw);
        // prefetch next tile's g row (L2-hit, hides under exp2/cvt)
        if (t + 1 < 16 && !hi)
            araw = *(const short8v*)(gbase + (size_t)(qw + (t + 1) * 32 + l31) * KP);

        f32x16 c = __builtin_amdgcn_mfma_f32_32x32x16_bf16(
            afrag, bfrag, czero, 0, 0, 0);
#pragma unroll
        for (int r = 0; r < 16; ++r) c[r] = __builtin_amdgcn_exp2f(c[r]);

        bf16x8 elo, ehi;
#pragma unroll
        for (int r = 0; r < 8; ++r) { elo[r] = (__bf16)c[r]; ehi[r] = (__bf16)c[r + 8]; }

        const int qbase = qw + (t << 5);
        const ushort* ap = (l31 == 1) ? ones_lds : (s_lds + qbase + (hi << 3));
        bf16x8 a1 = __builtin_bit_cast(bf16x8, *(const short8v*)ap);
        bf16x8 a2 = __builtin_bit_cast(bf16x8, *(const short8v*)(ap + 16));

        c_pv = __builtin_amdgcn_mfma_f32_32x32x16_bf16(a1, elo, c_pv, 0, 0, 0);
        c_pv = __builtin_amdgcn_mfma_f32_32x32x16_bf16(a2, ehi, c_pv, 0, 0, 0);
    }

    // partials: D rows 0 = sum e*s, 1 = sum e (regs 0,1 of hi=0 lanes)
    if (!hi) {
        part_a[w][l31] = c_pv[0];
        part_l[w][l31] = c_pv[1];
    }
    __syncthreads();

    // merge + att_map output
    if (tid < PTILE) {
        float l = 0.f, a = 0.f;
#pragma unroll
        for (int j = 0; j < 8; ++j) { l += part_l[j][tid]; a += part_a[j][tid]; }
        float att = a / l;
        att_lds[tid] = att;
        out[(size_t)n * HWP + p0 + tid] = att;
    }
    __syncthreads();

    // epilogue: out = att*gamma + x (x is L3-resident after proj's read)
    const float gm = gamma[0];
    const float* xn = x + (size_t)n * CH * HWP + p0;
    float* outp = out + NHW + (size_t)n * CH * HWP + p0;
    {
        int c  = tid >> 3;             // 512 float4s over (c, p/4), 1/thread
        int p4 = (tid & 7) << 2;
        float4 xv = *(const float4*)(xn + (size_t)c * HWP + p4);
        float4 av = *(const float4*)(att_lds + p4);
        float4 o;
        o.x = fmaf(av.x, gm, xv.x);
        o.y = fmaf(av.y, gm, xv.y);
        o.z = fmaf(av.z, gm, xv.z);
        o.w = fmaf(av.w, gm, xv.w);
        *(float4*)(outp + (size_t)c * HWP + p4) = o;
    }
}

extern "C" void kernel_launch(void* const* d_in, const int* in_sizes, int n_in,
                              void* d_out, int out_size, void* d_ws, size_t ws_size,
                              hipStream_t stream) {
    const float* x     = (const float*)d_in[0];
    const float* Wf    = (const float*)d_in[1];
    const float* bf    = (const float*)d_in[2];
    const float* Wg    = (const float*)d_in[3];
    const float* bg    = (const float*)d_in[4];
    const float* Ws    = (const float*)d_in[5];
    const float* bs    = (const float*)d_in[6];
    const float* gamma = (const float*)d_in[7];
    float* out = (float*)d_out;
    float* ws  = (float*)d_ws;

    // d_out layout: att_map [NB*HWP] then output [NB*CH*HWP]
    proj_kernel<<<NB * (HWP / 128), 512, 0, stream>>>(x, Wf, bf, Wg, bg, Ws, bs, ws);
    attn_finish_kernel<<<NB * (HWP / PTILE), 512, 0, stream>>>(x, gamma, ws, out);
}